// Round 5
// baseline (169.557 us; speedup 1.0000x reference)
//
#include <hip/hip_runtime.h>
#include <math.h>

// SO3 convolution lmax=2 — 2-dispatch pipeline, 4-wave block-per-atom.
//   K1) csr_kernel: ONE block (1024 thr). LDS histogram of idx_i; one 32-bit
//       shfl wave-scan (2 barriers) -> offsets[A+1]; scatter into a 48 KB LDS
//       staging buffer; coalesced dump -> esorted.
//   K2) so3_atom_kernel: grid = A, 256 threads = 4 waves per atom. The atom's
//       edges split into TEDGE=8 tiles; wave w handles tiles w, w+4, ... in a
//       PRIVATE LDS section (M, Ysh, rad, cut, j) with its own register acc.
//       Round count K = ceil(T/4) is block-uniform -> intra-loop barriers are
//       legal; empty tiles are exact zeros (cut=0, rad=0, M=0, j=self).
//       Per tile: B1 radial filters for 8 slots in one Wf pass (registers),
//       B2 sparse-CG M[9][12] per edge (8 lanes/edge, LDS atomics),
//       C branch-free unrolled 8-edge contraction.
//       Epilogue: waves 1-3 dump acc into the (reused) M region, wave 0 sums
//       and stores the atom's out row once. No slots, no reduce kernel,
//       no global atomics, no memsets.

#define S9     9
#define MROW   12          // padded M row stride (floats)
#define NF     128
#define NRAD   20
#define TEDGE  8           // edges per tile
#define WAVES  4
#define MAXA   2048
#define EMAX   12288       // LDS staging capacity for esorted

__device__ inline float2 f2fma(float a, float2 b, float2 c) {
    return make_float2(fmaf(a, b.x, c.x), fmaf(a, b.y, c.y));
}

// ---------- K1: CSR build (single block, 1024 threads, A <= 2048) ----------
__global__ __launch_bounds__(1024) void csr_kernel(
    const int* __restrict__ idx_i, int E, int A,
    int* __restrict__ offsets,      // [A+1]
    int* __restrict__ esorted)      // [E]
{
    __shared__ int lcnt[MAXA];      // counts, then reused as scatter cursors
    __shared__ int wtot[16];
    __shared__ int esh[EMAX];       // LDS-staged esorted (coalesced dump)
    const int t = threadIdx.x;
    const int lane = t & 63;
    const int wid  = t >> 6;

    for (int i = t; i < A; i += 1024) lcnt[i] = 0;
    __syncthreads();
    for (int e = t; e < E; e += 1024) atomicAdd(&lcnt[idx_i[e]], 1);
    __syncthreads();

    const int i0 = 2 * t, i1 = 2 * t + 1;
    const int ca = (i0 < A) ? lcnt[i0] : 0;
    const int cb = (i1 < A) ? lcnt[i1] : 0;
    __syncthreads();                 // all reads done before cursor overwrite

    // wave-level inclusive scan of (ca+cb), then 16-wave combine
    int inc = ca + cb;
    #pragma unroll
    for (int d = 1; d < 64; d <<= 1) {
        int u = __shfl_up(inc, d);
        if (lane >= d) inc += u;
    }
    if (lane == 63) wtot[wid] = inc;
    __syncthreads();
    if (wid == 0) {
        int w = (lane < 16) ? wtot[lane] : 0;
        #pragma unroll
        for (int d = 1; d < 16; d <<= 1) {
            int u = __shfl_up(w, d);
            if (lane >= d) w += u;
        }
        if (lane < 16) wtot[lane] = w;   // inclusive over wave totals
    }
    __syncthreads();
    int run = ((wid > 0) ? wtot[wid - 1] : 0) + (inc - (ca + cb));
    if (i0 < A) { offsets[i0] = run; lcnt[i0] = run; run += ca; }
    if (i1 < A) { offsets[i1] = run; lcnt[i1] = run; run += cb; }
    if (t == 1023) offsets[A] = wtot[15];
    __syncthreads();

    if (E <= EMAX) {
        for (int e = t; e < E; e += 1024) {
            int p = atomicAdd(&lcnt[idx_i[e]], 1);
            esh[p] = e;
        }
        __syncthreads();
        for (int i = t; i < E; i += 1024) esorted[i] = esh[i];   // coalesced
    } else {
        for (int e = t; e < E; e += 1024) {
            int p = atomicAdd(&lcnt[idx_i[e]], 1);
            esorted[p] = e;
        }
    }
}

// ---------- K2: 4 waves per atom, wave-parallel tiles ----------
__global__ __launch_bounds__(256) void so3_atom_kernel(
    const float* __restrict__ x,        // [A, 9, 128]
    const float* __restrict__ radial,   // [E, 20]
    const float* __restrict__ dir,      // [E, 3]
    const float* __restrict__ cutoff,   // [E]
    const float* __restrict__ Wf,       // [20, 384]
    const float* __restrict__ bf,       // [384]
    const float* __restrict__ cg_vals,
    const int* __restrict__ idx_j,
    const int* __restrict__ cg_i1,
    const int* __restrict__ cg_i2,
    const int* __restrict__ cg_i3,
    int ncg,
    const int* __restrict__ offsets,    // [A+1]
    const int* __restrict__ esorted,    // [E]
    float* __restrict__ out)            // [A, 9, 128]
{
    const int a = blockIdx.x;
    const int t = threadIdx.x;
    const int lane = t & 63;             // f-pair index: f = 2*lane, 2*lane+1
    const int wid  = t >> 6;
    const int e0 = offsets[a];
    const int e1 = offsets[a + 1];
    const int T = (e1 - e0 + TEDGE - 1) / TEDGE;      // tiles for this atom
    const int K = (T + WAVES - 1) / WAVES;            // block-uniform rounds

    __shared__ __align__(16) float M[WAVES][TEDGE][MROW * S9];  // 13824 B
    __shared__ float Ysh[WAVES][TEDGE][S9];
    __shared__ float radsh[WAVES][TEDGE][NRAD];
    __shared__ float cutsh[WAVES][TEDGE];
    __shared__ int   jsh[WAVES][TEDGE];

    float2 acc[S9];
    #pragma unroll
    for (int s = 0; s < S9; ++s) acc[s] = make_float2(0.f, 0.f);

    // bias rows are tile-invariant
    const float2 b0 = ((const float2*)(bf + 0 * NF))[lane];
    const float2 b1 = ((const float2*)(bf + 1 * NF))[lane];
    const float2 b2 = ((const float2*)(bf + 2 * NF))[lane];

    for (int k = 0; k < K; ++k) {
        const int tile = k * WAVES + wid;
        const int base = e0 + tile * TEDGE;
        const int n = min(TEDGE, max(0, e1 - base));   // 0 for overflow tiles

        // ---- stage (wave-private section): zero M, metadata, SH, radial ----
        {
            float4* Mz = (float4*)&M[wid][0][0];
            const int tot4 = TEDGE * MROW * S9 / 4;   // 216
            for (int qq = lane; qq < tot4; qq += 64) Mz[qq] = make_float4(0.f, 0.f, 0.f, 0.f);
        }
        if (lane < TEDGE) {
            int jj = a;              // empty slots: any valid row (contribution 0)
            float cut = 0.f;
            if (lane < n) {
                const int e = esorted[base + lane];
                jj = idx_j[e];
                cut = cutoff[e];
                float dx = dir[3 * e], dy = dir[3 * e + 1], dz = dir[3 * e + 2];
                const float inv = rsqrtf(dx * dx + dy * dy + dz * dz);
                dx *= inv; dy *= inv; dz *= inv;
                const float s3c  = 1.7320508075688772f;
                const float s5c  = 2.2360679774997896f;
                const float s15c = 3.8729833462074170f;
                Ysh[wid][lane][0] = 1.0f;
                Ysh[wid][lane][1] = s3c * dy;
                Ysh[wid][lane][2] = s3c * dz;
                Ysh[wid][lane][3] = s3c * dx;
                Ysh[wid][lane][4] = s15c * dx * dy;
                Ysh[wid][lane][5] = s15c * dy * dz;
                Ysh[wid][lane][6] = 0.5f * s5c * (3.0f * dz * dz - 1.0f);
                Ysh[wid][lane][7] = s15c * dx * dz;
                Ysh[wid][lane][8] = 0.5f * s15c * (dx * dx - dy * dy);
            }
            jsh[wid][lane] = jj;
            cutsh[wid][lane] = cut;
        }
        for (int qq = lane; qq < TEDGE * NRAD; qq += 64) {
            const int c = qq / NRAD;
            const int r = qq - c * NRAD;
            radsh[wid][c][r] = (c < n) ? radial[(size_t)esorted[base + c] * NRAD + r] : 0.f;
        }
        __syncthreads();

        // ---- B1: radial filters for 8 slots in one Wf pass (registers) ----
        float2 w[TEDGE][3];
        #pragma unroll
        for (int c = 0; c < TEDGE; ++c) { w[c][0] = b0; w[c][1] = b1; w[c][2] = b2; }
        #pragma unroll 4
        for (int r = 0; r < NRAD; ++r) {
            const float2* wrow = (const float2*)(Wf + r * (3 * NF));
            const float2 w0 = wrow[lane];
            const float2 w1 = wrow[lane + 64];
            const float2 w2 = wrow[lane + 128];
            #pragma unroll
            for (int c = 0; c < TEDGE; ++c) {
                const float rv = radsh[wid][c][r];   // 0 for c >= n
                w[c][0] = f2fma(rv, w0, w[c][0]);
                w[c][1] = f2fma(rv, w1, w[c][1]);
                w[c][2] = f2fma(rv, w2, w[c][2]);
            }
        }
        #pragma unroll
        for (int c = 0; c < TEDGE; ++c) {
            const float cut = cutsh[wid][c];         // 0 for c >= n -> w row = 0
            w[c][0].x *= cut; w[c][0].y *= cut;
            w[c][1].x *= cut; w[c][1].y *= cut;
            w[c][2].x *= cut; w[c][2].y *= cut;
        }

        // ---- B2: build M for this wave's n edges (8 lanes per edge) ----
        {
            const int c = lane >> 3;
            const int r = lane & 7;
            if (c < n) {
                for (int kk = r; kk < ncg; kk += 8) {
                    atomicAdd(&M[wid][c][cg_i3[kk] * MROW + cg_i1[kk]],
                              cg_vals[kk] * Ysh[wid][c][cg_i2[kk]]);
                }
            }
        }
        __syncthreads();

        // ---- C: branch-free fully-unrolled 8-edge contraction ----
        #pragma unroll
        for (int c = 0; c < TEDGE; ++c) {
            const int j = __builtin_amdgcn_readfirstlane(jsh[wid][c]);

            const float2* xp = (const float2*)(x + (size_t)j * (S9 * NF)) + lane;
            float2 xj[S9];
            #pragma unroll
            for (int s = 0; s < S9; ++s) xj[s] = xp[s * 64];

            #pragma unroll
            for (int s3 = 0; s3 < S9; ++s3) {
                const float4* mr = (const float4*)&M[wid][c][s3 * MROW];
                const float4 m0 = mr[0];
                const float4 m1 = mr[1];
                const float  m8 = M[wid][c][s3 * MROW + 8];
                float2 tsum = make_float2(0.f, 0.f);
                tsum = f2fma(m0.x, xj[0], tsum);
                tsum = f2fma(m0.y, xj[1], tsum);
                tsum = f2fma(m0.z, xj[2], tsum);
                tsum = f2fma(m0.w, xj[3], tsum);
                tsum = f2fma(m1.x, xj[4], tsum);
                tsum = f2fma(m1.y, xj[5], tsum);
                tsum = f2fma(m1.z, xj[6], tsum);
                tsum = f2fma(m1.w, xj[7], tsum);
                tsum = f2fma(m8,   xj[8], tsum);
                const float2 wl = (s3 == 0) ? w[c][0] : ((s3 < 4) ? w[c][1] : w[c][2]);
                acc[s3].x = fmaf(wl.x, tsum.x, acc[s3].x);
                acc[s3].y = fmaf(wl.y, tsum.y, acc[s3].y);
            }
        }
        __syncthreads();     // protect wave sections before next round
    }

    // ---- cross-wave reduce (reuse M region: 3 x 1152 floats = 13824 B) ----
    float* red = &M[0][0][0];
    if (wid > 0) {
        float2* rp = (float2*)(red + (size_t)(wid - 1) * (S9 * NF)) + lane;
        #pragma unroll
        for (int s = 0; s < S9; ++s) rp[s * 64] = acc[s];
    }
    __syncthreads();
    if (wid == 0) {
        #pragma unroll
        for (int r2 = 0; r2 < WAVES - 1; ++r2) {
            const float2* rp = (const float2*)(red + (size_t)r2 * (S9 * NF)) + lane;
            #pragma unroll
            for (int s = 0; s < S9; ++s) {
                float2 v = rp[s * 64];
                acc[s].x += v.x; acc[s].y += v.y;
            }
        }
        float2* op = (float2*)(out + (size_t)a * (S9 * NF)) + lane;
        #pragma unroll
        for (int s = 0; s < S9; ++s) op[s * 64] = acc[s];
    }
}

extern "C" void kernel_launch(void* const* d_in, const int* in_sizes, int n_in,
                              void* d_out, int out_size, void* d_ws, size_t ws_size,
                              hipStream_t stream) {
    const float* x       = (const float*)d_in[0];
    const float* radial  = (const float*)d_in[1];
    const float* dir     = (const float*)d_in[2];
    const float* cutoff  = (const float*)d_in[3];
    const float* Wf      = (const float*)d_in[4];
    const float* bf      = (const float*)d_in[5];
    const float* cg_vals = (const float*)d_in[6];
    const int*   idx_i   = (const int*)d_in[7];
    const int*   idx_j   = (const int*)d_in[8];
    const int*   cg_i1   = (const int*)d_in[9];
    const int*   cg_i2   = (const int*)d_in[10];
    const int*   cg_i3   = (const int*)d_in[11];
    // d_in[12] = w_idx: unused (w_idx[k] == l(cg_idx_out[k]), folded into kernel)

    const int E   = in_sizes[7];
    const int ncg = in_sizes[6];
    const int A   = in_sizes[0] / (S9 * NF);

    // ws ints: offsets[A+1] | esorted[E]
    int* offsets = (int*)d_ws;
    int* esorted = offsets + (A + 1);

    csr_kernel<<<1, 1024, 0, stream>>>(idx_i, E, A, offsets, esorted);

    so3_atom_kernel<<<A, 256, 0, stream>>>(
        x, radial, dir, cutoff, Wf, bf, cg_vals, idx_j,
        cg_i1, cg_i2, cg_i3, ncg, offsets, esorted, (float*)d_out);
}

// Round 6
// 146.599 us; speedup vs baseline: 1.1566x; 1.1566x over previous
//
#include <hip/hip_runtime.h>
#include <math.h>

// SO3 convolution lmax=2 — 2-dispatch pipeline, (atom x feature-half) blocks.
//   K1) csr_kernel: ONE block (1024 thr). LDS histogram of idx_i; one 32-bit
//       shfl wave-scan (2 barriers) -> offsets[A+1]; scatter into a 48 KB LDS
//       staging buffer; coalesced dump -> esorted.
//   K2) so3_atom_kernel: grid = 2*A, ONE 64-thread wave per (atom, f-half).
//       Each lane owns ONE feature (f = fh*64 + lane, scalar f32 path).
//       Loops over tiles of TEDGE=8 edges; per tile:
//         stage (Ysh, radial, cutoff, j; tail slots exact zeros),
//         B1 radial filters for 8 slots in one Wf pass (registers; the radial
//            GEMM splits across f-halves -> no duplicated FLOPs),
//         B2 sparse-CG M[9][12] per edge in LDS (8 lanes/edge),
//         C  contraction in two 4-edge groups: burst-issue 36 x-loads, then
//            FMA burst (one latency window per group instead of per edge).
//       Register accumulator across tiles; single direct store to out
//       (deg-0 atoms store zeros). No slots, no reduce kernel, no global
//       atomics, no memsets.

#define S9     9
#define MROW   12          // padded M row stride (floats)
#define NF     128
#define NRAD   20
#define TEDGE  8           // edges per tile
#define MAXA   2048
#define EMAX   12288       // LDS staging capacity for esorted

// ---------- K1: CSR build (single block, 1024 threads, A <= 2048) ----------
__global__ __launch_bounds__(1024) void csr_kernel(
    const int* __restrict__ idx_i, int E, int A,
    int* __restrict__ offsets,      // [A+1]
    int* __restrict__ esorted)      // [E]
{
    __shared__ int lcnt[MAXA];      // counts, then reused as scatter cursors
    __shared__ int wtot[16];
    __shared__ int esh[EMAX];       // LDS-staged esorted (coalesced dump)
    const int t = threadIdx.x;
    const int lane = t & 63;
    const int wid  = t >> 6;

    for (int i = t; i < A; i += 1024) lcnt[i] = 0;
    __syncthreads();
    for (int e = t; e < E; e += 1024) atomicAdd(&lcnt[idx_i[e]], 1);
    __syncthreads();

    const int i0 = 2 * t, i1 = 2 * t + 1;
    const int ca = (i0 < A) ? lcnt[i0] : 0;
    const int cb = (i1 < A) ? lcnt[i1] : 0;
    __syncthreads();                 // all reads done before cursor overwrite

    // wave-level inclusive scan of (ca+cb), then 16-wave combine
    int inc = ca + cb;
    #pragma unroll
    for (int d = 1; d < 64; d <<= 1) {
        int u = __shfl_up(inc, d);
        if (lane >= d) inc += u;
    }
    if (lane == 63) wtot[wid] = inc;
    __syncthreads();
    if (wid == 0) {
        int w = (lane < 16) ? wtot[lane] : 0;
        #pragma unroll
        for (int d = 1; d < 16; d <<= 1) {
            int u = __shfl_up(w, d);
            if (lane >= d) w += u;
        }
        if (lane < 16) wtot[lane] = w;   // inclusive over wave totals
    }
    __syncthreads();
    int run = ((wid > 0) ? wtot[wid - 1] : 0) + (inc - (ca + cb));
    if (i0 < A) { offsets[i0] = run; lcnt[i0] = run; run += ca; }
    if (i1 < A) { offsets[i1] = run; lcnt[i1] = run; run += cb; }
    if (t == 1023) offsets[A] = wtot[15];
    __syncthreads();

    if (E <= EMAX) {
        for (int e = t; e < E; e += 1024) {
            int p = atomicAdd(&lcnt[idx_i[e]], 1);
            esh[p] = e;
        }
        __syncthreads();
        for (int i = t; i < E; i += 1024) esorted[i] = esh[i];   // coalesced
    } else {
        for (int e = t; e < E; e += 1024) {
            int p = atomicAdd(&lcnt[idx_i[e]], 1);
            esorted[p] = e;
        }
    }
}

// ---------- K2: one wave per (atom, feature-half) ----------
__global__ __launch_bounds__(64) void so3_atom_kernel(
    const float* __restrict__ x,        // [A, 9, 128]
    const float* __restrict__ radial,   // [E, 20]
    const float* __restrict__ dir,      // [E, 3]
    const float* __restrict__ cutoff,   // [E]
    const float* __restrict__ Wf,       // [20, 384]
    const float* __restrict__ bf,       // [384]
    const float* __restrict__ cg_vals,
    const int* __restrict__ idx_j,
    const int* __restrict__ cg_i1,
    const int* __restrict__ cg_i2,
    const int* __restrict__ cg_i3,
    int ncg,
    const int* __restrict__ offsets,    // [A+1]
    const int* __restrict__ esorted,    // [E]
    float* __restrict__ out)            // [A, 9, 128]
{
    const int a  = blockIdx.x >> 1;
    const int fh = blockIdx.x & 1;
    const int t  = threadIdx.x;
    const int f  = fh * 64 + t;          // this lane's feature
    const int e0 = offsets[a];
    const int e1 = offsets[a + 1];

    __shared__ __align__(16) float M[TEDGE][MROW * S9];
    __shared__ float Ysh[TEDGE][S9];
    __shared__ float radsh[TEDGE][NRAD];
    __shared__ float cutsh[TEDGE];
    __shared__ int   jsh[TEDGE];

    float acc[S9];
    #pragma unroll
    for (int s = 0; s < S9; ++s) acc[s] = 0.f;

    // bias values are tile-invariant
    const float b0 = bf[0 * NF + f];
    const float b1 = bf[1 * NF + f];
    const float b2 = bf[2 * NF + f];

    for (int base = e0; base < e1; base += TEDGE) {
        const int n = min(TEDGE, e1 - base);

        // ---- stage: zero M, per-slot metadata, SH, radial ----
        {
            float4* Mz = (float4*)&M[0][0];
            const int tot4 = TEDGE * MROW * S9 / 4;   // 216
            for (int qq = t; qq < tot4; qq += 64) Mz[qq] = make_float4(0.f, 0.f, 0.f, 0.f);
        }
        if (t < TEDGE) {
            int jj = a;              // tail slots: any valid row (contribution 0)
            float cut = 0.f;
            if (t < n) {
                const int e = esorted[base + t];
                jj = idx_j[e];
                cut = cutoff[e];
                float dx = dir[3 * e], dy = dir[3 * e + 1], dz = dir[3 * e + 2];
                const float inv = rsqrtf(dx * dx + dy * dy + dz * dz);
                dx *= inv; dy *= inv; dz *= inv;
                const float s3c  = 1.7320508075688772f;
                const float s5c  = 2.2360679774997896f;
                const float s15c = 3.8729833462074170f;
                Ysh[t][0] = 1.0f;
                Ysh[t][1] = s3c * dy;
                Ysh[t][2] = s3c * dz;
                Ysh[t][3] = s3c * dx;
                Ysh[t][4] = s15c * dx * dy;
                Ysh[t][5] = s15c * dy * dz;
                Ysh[t][6] = 0.5f * s5c * (3.0f * dz * dz - 1.0f);
                Ysh[t][7] = s15c * dx * dz;
                Ysh[t][8] = 0.5f * s15c * (dx * dx - dy * dy);
            }
            jsh[t] = jj;
            cutsh[t] = cut;
        }
        for (int qq = t; qq < TEDGE * NRAD; qq += 64) {
            const int c = qq / NRAD;
            const int r = qq - c * NRAD;
            radsh[c][r] = (c < n) ? radial[(size_t)esorted[base + c] * NRAD + r] : 0.f;
        }
        __syncthreads();

        // ---- B1: radial filters for 8 slots, this lane's feature only ----
        float w[TEDGE][3];
        #pragma unroll
        for (int c = 0; c < TEDGE; ++c) { w[c][0] = b0; w[c][1] = b1; w[c][2] = b2; }
        #pragma unroll 4
        for (int r = 0; r < NRAD; ++r) {
            const float* wrow = Wf + r * (3 * NF) + f;
            const float w0 = wrow[0];
            const float w1 = wrow[NF];
            const float w2 = wrow[2 * NF];
            #pragma unroll
            for (int c = 0; c < TEDGE; ++c) {
                const float rv = radsh[c][r];   // 0 for c >= n
                w[c][0] = fmaf(rv, w0, w[c][0]);
                w[c][1] = fmaf(rv, w1, w[c][1]);
                w[c][2] = fmaf(rv, w2, w[c][2]);
            }
        }
        #pragma unroll
        for (int c = 0; c < TEDGE; ++c) {
            const float cut = cutsh[c];          // 0 for c >= n -> w row = 0
            w[c][0] *= cut; w[c][1] *= cut; w[c][2] *= cut;
        }

        // ---- B2: build M for all n edges (8 lanes per edge) ----
        {
            const int c = t >> 3;
            const int r = t & 7;
            if (c < n) {
                for (int kk = r; kk < ncg; kk += 8) {
                    atomicAdd(&M[c][cg_i3[kk] * MROW + cg_i1[kk]],
                              cg_vals[kk] * Ysh[c][cg_i2[kk]]);
                }
            }
        }
        __syncthreads();

        // ---- C: two 4-edge groups; burst-issue 36 x-loads then FMA burst ----
        #pragma unroll
        for (int g = 0; g < 2; ++g) {
            float xj[4][S9];
            #pragma unroll
            for (int c2 = 0; c2 < 4; ++c2) {
                const int j = __builtin_amdgcn_readfirstlane(jsh[g * 4 + c2]);
                const float* xp = x + (size_t)j * (S9 * NF) + f;
                #pragma unroll
                for (int s = 0; s < S9; ++s) xj[c2][s] = xp[s * NF];
            }
            #pragma unroll
            for (int c2 = 0; c2 < 4; ++c2) {
                const int c = g * 4 + c2;
                #pragma unroll
                for (int s3 = 0; s3 < S9; ++s3) {
                    const float4* mr = (const float4*)&M[c][s3 * MROW];
                    const float4 m0 = mr[0];
                    const float4 m1 = mr[1];
                    const float  m8 = M[c][s3 * MROW + 8];
                    float ts = m0.x * xj[c2][0];
                    ts = fmaf(m0.y, xj[c2][1], ts);
                    ts = fmaf(m0.z, xj[c2][2], ts);
                    ts = fmaf(m0.w, xj[c2][3], ts);
                    ts = fmaf(m1.x, xj[c2][4], ts);
                    ts = fmaf(m1.y, xj[c2][5], ts);
                    ts = fmaf(m1.z, xj[c2][6], ts);
                    ts = fmaf(m1.w, xj[c2][7], ts);
                    ts = fmaf(m8,   xj[c2][8], ts);
                    const float wl = (s3 == 0) ? w[c][0] : ((s3 < 4) ? w[c][1] : w[c][2]);
                    acc[s3] = fmaf(wl, ts, acc[s3]);
                }
            }
        }
        __syncthreads();     // protect LDS before next tile overwrites
    }

    // ---- store this (atom, f-half) output slice (zeros for deg-0) ----
    float* op = out + (size_t)a * (S9 * NF) + f;
    #pragma unroll
    for (int s = 0; s < S9; ++s) op[s * NF] = acc[s];
}

extern "C" void kernel_launch(void* const* d_in, const int* in_sizes, int n_in,
                              void* d_out, int out_size, void* d_ws, size_t ws_size,
                              hipStream_t stream) {
    const float* x       = (const float*)d_in[0];
    const float* radial  = (const float*)d_in[1];
    const float* dir     = (const float*)d_in[2];
    const float* cutoff  = (const float*)d_in[3];
    const float* Wf      = (const float*)d_in[4];
    const float* bf      = (const float*)d_in[5];
    const float* cg_vals = (const float*)d_in[6];
    const int*   idx_i   = (const int*)d_in[7];
    const int*   idx_j   = (const int*)d_in[8];
    const int*   cg_i1   = (const int*)d_in[9];
    const int*   cg_i2   = (const int*)d_in[10];
    const int*   cg_i3   = (const int*)d_in[11];
    // d_in[12] = w_idx: unused (w_idx[k] == l(cg_idx_out[k]), folded into kernel)

    const int E   = in_sizes[7];
    const int ncg = in_sizes[6];
    const int A   = in_sizes[0] / (S9 * NF);

    // ws ints: offsets[A+1] | esorted[E]
    int* offsets = (int*)d_ws;
    int* esorted = offsets + (A + 1);

    csr_kernel<<<1, 1024, 0, stream>>>(idx_i, E, A, offsets, esorted);

    so3_atom_kernel<<<2 * A, 64, 0, stream>>>(
        x, radial, dir, cutoff, Wf, bf, cg_vals, idx_j,
        cg_i1, cg_i2, cg_i3, ncg, offsets, esorted, (float*)d_out);
}

// Round 7
// 135.690 us; speedup vs baseline: 1.2496x; 1.0804x over previous
//
#include <hip/hip_runtime.h>
#include <math.h>

// SO3 convolution lmax=2 — 3-dispatch, phase-split by natural parallelism.
//   K1) csr_kernel: ONE block (1024 thr). LDS histogram + shfl-scan ->
//       offsets[A+1]; LDS-staged scatter -> esorted. (unchanged)
//   KA) so3_edge_kernel: ONE wave per edge (grid E/4 x 256). Computes Y,
//       sparse-CG M[9][12] in wave-private LDS (~2 atomics/lane), and the
//       full radial filter Wij[e,3,128] (radial GEMM, 6 chains/lane).
//       Writes Mws[E][108] + Wws[E][384] to workspace. Per-edge setup done
//       ONCE, at 47 waves/CU -> latency fully hidden.
//   KB) so3_gather_kernel: 128 thr (2 waves = 2 f-halves) per atom.
//       Edge ids + j prefetched per 96-edge window into LDS (one dependent
//       chain per block, not per tile). Per 8-edge tile: float4-stage M-tile
//       from ws (L2-hot), per-lane W regs, burst x-gather, FMA contraction.
//       No B1/B2/atomics in the atom kernel. Direct store (deg-0 -> zeros).

#define S9     9
#define MROW   12              // padded M row stride (floats)
#define MSZ    (S9 * MROW)     // 108 floats per edge
#define NF     128
#define NRAD   20
#define TEDGE  8               // edges per tile in KB
#define WIN    96              // edge window prefetched into LDS in KB
#define MAXA   2048
#define EMAX   12288           // LDS staging capacity for esorted in K1

// ---------- K1: CSR build (single block, 1024 threads, A <= 2048) ----------
__global__ __launch_bounds__(1024) void csr_kernel(
    const int* __restrict__ idx_i, int E, int A,
    int* __restrict__ offsets,      // [A+1]
    int* __restrict__ esorted)      // [E]
{
    __shared__ int lcnt[MAXA];      // counts, then reused as scatter cursors
    __shared__ int wtot[16];
    __shared__ int esh[EMAX];       // LDS-staged esorted (coalesced dump)
    const int t = threadIdx.x;
    const int lane = t & 63;
    const int wid  = t >> 6;

    for (int i = t; i < A; i += 1024) lcnt[i] = 0;
    __syncthreads();
    for (int e = t; e < E; e += 1024) atomicAdd(&lcnt[idx_i[e]], 1);
    __syncthreads();

    const int i0 = 2 * t, i1 = 2 * t + 1;
    const int ca = (i0 < A) ? lcnt[i0] : 0;
    const int cb = (i1 < A) ? lcnt[i1] : 0;
    __syncthreads();                 // all reads done before cursor overwrite

    int inc = ca + cb;
    #pragma unroll
    for (int d = 1; d < 64; d <<= 1) {
        int u = __shfl_up(inc, d);
        if (lane >= d) inc += u;
    }
    if (lane == 63) wtot[wid] = inc;
    __syncthreads();
    if (wid == 0) {
        int w = (lane < 16) ? wtot[lane] : 0;
        #pragma unroll
        for (int d = 1; d < 16; d <<= 1) {
            int u = __shfl_up(w, d);
            if (lane >= d) w += u;
        }
        if (lane < 16) wtot[lane] = w;
    }
    __syncthreads();
    int run = ((wid > 0) ? wtot[wid - 1] : 0) + (inc - (ca + cb));
    if (i0 < A) { offsets[i0] = run; lcnt[i0] = run; run += ca; }
    if (i1 < A) { offsets[i1] = run; lcnt[i1] = run; run += cb; }
    if (t == 1023) offsets[A] = wtot[15];
    __syncthreads();

    if (E <= EMAX) {
        for (int e = t; e < E; e += 1024) {
            int p = atomicAdd(&lcnt[idx_i[e]], 1);
            esh[p] = e;
        }
        __syncthreads();
        for (int i = t; i < E; i += 1024) esorted[i] = esh[i];   // coalesced
    } else {
        for (int e = t; e < E; e += 1024) {
            int p = atomicAdd(&lcnt[idx_i[e]], 1);
            esorted[p] = e;
        }
    }
}

// ---------- KA: one wave per edge — M + Wij precompute ----------
__global__ __launch_bounds__(256) void so3_edge_kernel(
    const float* __restrict__ radial,   // [E, 20]
    const float* __restrict__ dir,      // [E, 3]
    const float* __restrict__ cutoff,   // [E]
    const float* __restrict__ Wf,       // [20, 384]
    const float* __restrict__ bf,       // [384]
    const float* __restrict__ cg_vals,
    const int* __restrict__ cg_i1,
    const int* __restrict__ cg_i2,
    const int* __restrict__ cg_i3,
    int ncg, int E,
    float* __restrict__ Mws,            // [E, 108]
    float* __restrict__ Wws)            // [E, 384]
{
    const int wid  = threadIdx.x >> 6;
    const int lane = threadIdx.x & 63;
    const int e = blockIdx.x * 4 + wid;
    if (e >= E) return;                 // whole wave exits; no barriers in KA

    __shared__ __align__(16) float Msh[4][MSZ];   // wave-private sections
    __shared__ float Ysh[4][S9];

    // zero this wave's M section (27 float4)
    if (lane < 27) ((float4*)&Msh[wid][0])[lane] = make_float4(0.f, 0.f, 0.f, 0.f);

    // uniform edge data -> Y (lane 0 writes LDS; same-wave DS is in-order)
    float dx = dir[3 * e], dy = dir[3 * e + 1], dz = dir[3 * e + 2];
    const float inv = rsqrtf(dx * dx + dy * dy + dz * dz);
    dx *= inv; dy *= inv; dz *= inv;
    const float s3c  = 1.7320508075688772f;
    const float s5c  = 2.2360679774997896f;
    const float s15c = 3.8729833462074170f;
    if (lane == 0) {
        Ysh[wid][0] = 1.0f;
        Ysh[wid][1] = s3c * dy;
        Ysh[wid][2] = s3c * dz;
        Ysh[wid][3] = s3c * dx;
        Ysh[wid][4] = s15c * dx * dy;
        Ysh[wid][5] = s15c * dy * dz;
        Ysh[wid][6] = 0.5f * s5c * (3.0f * dz * dz - 1.0f);
        Ysh[wid][7] = s15c * dx * dz;
        Ysh[wid][8] = 0.5f * s15c * (dx * dx - dy * dy);
    }

    float rad[NRAD];
    #pragma unroll
    for (int r = 0; r < NRAD; ++r) rad[r] = radial[(size_t)e * NRAD + r];
    const float cut = cutoff[e];

    // sparse-CG M build: ~2.3 LDS atomics per lane, wave-private section
    for (int k = lane; k < ncg; k += 64) {
        atomicAdd(&Msh[wid][cg_i3[k] * MROW + cg_i1[k]],
                  cg_vals[k] * Ysh[wid][cg_i2[k]]);
    }

    // radial filter: 6 outputs per lane (l=0..2, f=lane / lane+64)
    const int f0 = lane, f1 = lane + 64;
    float a00 = bf[0 * NF + f0], a01 = bf[0 * NF + f1];
    float a10 = bf[1 * NF + f0], a11 = bf[1 * NF + f1];
    float a20 = bf[2 * NF + f0], a21 = bf[2 * NF + f1];
    #pragma unroll 4
    for (int r = 0; r < NRAD; ++r) {
        const float* wr = Wf + r * (3 * NF);
        a00 = fmaf(rad[r], wr[0 * NF + f0], a00);
        a01 = fmaf(rad[r], wr[0 * NF + f1], a01);
        a10 = fmaf(rad[r], wr[1 * NF + f0], a10);
        a11 = fmaf(rad[r], wr[1 * NF + f1], a11);
        a20 = fmaf(rad[r], wr[2 * NF + f0], a20);
        a21 = fmaf(rad[r], wr[2 * NF + f1], a21);
    }
    float* wout = Wws + (size_t)e * (3 * NF);
    wout[0 * NF + f0] = a00 * cut; wout[0 * NF + f1] = a01 * cut;
    wout[1 * NF + f0] = a10 * cut; wout[1 * NF + f1] = a11 * cut;
    wout[2 * NF + f0] = a20 * cut; wout[2 * NF + f1] = a21 * cut;

    // dump M (same-wave DS ordering guarantees atomics landed)
    if (lane < 27) {
        float4 v = ((const float4*)&Msh[wid][0])[lane];
        ((float4*)(Mws + (size_t)e * MSZ))[lane] = v;
    }
}

// ---------- KB: 128 thr (2 f-half waves) per atom — gather + contract ----------
__global__ __launch_bounds__(128) void so3_gather_kernel(
    const float* __restrict__ x,        // [A, 9, 128]
    const float* __restrict__ Mws,      // [E, 108]
    const float* __restrict__ Wws,      // [E, 384]
    const int* __restrict__ idx_j,
    const int* __restrict__ offsets,    // [A+1]
    const int* __restrict__ esorted,    // [E]
    float* __restrict__ out)            // [A, 9, 128]
{
    const int a    = blockIdx.x;
    const int t    = threadIdx.x;
    const int lane = t & 63;
    const int fh   = t >> 6;
    const int f    = fh * 64 + lane;     // this lane's feature
    const int e0 = offsets[a];
    const int e1 = offsets[a + 1];

    __shared__ __align__(16) float M2[TEDGE * MSZ];   // 864 floats
    __shared__ int eall[WIN], jall[WIN];

    float acc[S9];
    #pragma unroll
    for (int s = 0; s < S9; ++s) acc[s] = 0.f;

    for (int w0 = e0; w0 < e1; w0 += WIN) {
        const int wn = min(WIN, e1 - w0);
        __syncthreads();                 // protect eall/jall from prior readers
        for (int i = t; i < wn; i += 128) {
            const int e = esorted[w0 + i];
            eall[i] = e;
            jall[i] = idx_j[e];
        }
        __syncthreads();

        for (int base = 0; base < wn; base += TEDGE) {
            const int n = min(TEDGE, wn - base);

            // stage M tile: 216 float4, coalesced, L2-hot (just written by KA)
            for (int qq = t; qq < TEDGE * 27; qq += 128) {
                const int c = qq / 27;
                float4 v = make_float4(0.f, 0.f, 0.f, 0.f);
                if (c < n)
                    v = ((const float4*)(Mws + (size_t)eall[base + c] * MSZ))[qq - c * 27];
                ((float4*)M2)[qq] = v;
            }

            // per-lane W regs + uniform j regs (independent of M2 barrier)
            float wreg[TEDGE][3];
            int jreg[TEDGE];
            #pragma unroll
            for (int c = 0; c < TEDGE; ++c) {
                if (c < n) {
                    const float* wp = Wws + (size_t)eall[base + c] * (3 * NF) + f;
                    wreg[c][0] = wp[0];
                    wreg[c][1] = wp[NF];
                    wreg[c][2] = wp[2 * NF];
                    jreg[c] = __builtin_amdgcn_readfirstlane(jall[base + c]);
                } else {
                    wreg[c][0] = wreg[c][1] = wreg[c][2] = 0.f;   // exact zeros
                    jreg[c] = a;                                   // valid row
                }
            }
            __syncthreads();

            // contraction: two 4-edge groups, burst x-loads then FMA burst
            #pragma unroll
            for (int g = 0; g < 2; ++g) {
                float xj[4][S9];
                #pragma unroll
                for (int c2 = 0; c2 < 4; ++c2) {
                    const float* xp = x + (size_t)jreg[g * 4 + c2] * (S9 * NF) + f;
                    #pragma unroll
                    for (int s = 0; s < S9; ++s) xj[c2][s] = xp[s * NF];
                }
                #pragma unroll
                for (int c2 = 0; c2 < 4; ++c2) {
                    const int c = g * 4 + c2;
                    #pragma unroll
                    for (int s3 = 0; s3 < S9; ++s3) {
                        const float4* mr = (const float4*)&M2[c * MSZ + s3 * MROW];
                        const float4 m0 = mr[0];
                        const float4 m1 = mr[1];
                        const float  m8 = M2[c * MSZ + s3 * MROW + 8];
                        float ts = m0.x * xj[c2][0];
                        ts = fmaf(m0.y, xj[c2][1], ts);
                        ts = fmaf(m0.z, xj[c2][2], ts);
                        ts = fmaf(m0.w, xj[c2][3], ts);
                        ts = fmaf(m1.x, xj[c2][4], ts);
                        ts = fmaf(m1.y, xj[c2][5], ts);
                        ts = fmaf(m1.z, xj[c2][6], ts);
                        ts = fmaf(m1.w, xj[c2][7], ts);
                        ts = fmaf(m8,   xj[c2][8], ts);
                        const float wl = (s3 == 0) ? wreg[c][0]
                                       : ((s3 < 4) ? wreg[c][1] : wreg[c][2]);
                        acc[s3] = fmaf(wl, ts, acc[s3]);
                    }
                }
            }
            __syncthreads();     // protect M2 before next tile overwrites
        }
    }

    // store this (atom, f-half) output slice (zeros for deg-0 atoms)
    float* op = out + (size_t)a * (S9 * NF) + f;
    #pragma unroll
    for (int s = 0; s < S9; ++s) op[s * NF] = acc[s];
}

extern "C" void kernel_launch(void* const* d_in, const int* in_sizes, int n_in,
                              void* d_out, int out_size, void* d_ws, size_t ws_size,
                              hipStream_t stream) {
    const float* x       = (const float*)d_in[0];
    const float* radial  = (const float*)d_in[1];
    const float* dir     = (const float*)d_in[2];
    const float* cutoff  = (const float*)d_in[3];
    const float* Wf      = (const float*)d_in[4];
    const float* bf      = (const float*)d_in[5];
    const float* cg_vals = (const float*)d_in[6];
    const int*   idx_i   = (const int*)d_in[7];
    const int*   idx_j   = (const int*)d_in[8];
    const int*   cg_i1   = (const int*)d_in[9];
    const int*   cg_i2   = (const int*)d_in[10];
    const int*   cg_i3   = (const int*)d_in[11];
    // d_in[12] = w_idx: unused (w_idx[k] == l(cg_idx_out[k]), folded into kernel)

    const int E   = in_sizes[7];
    const int ncg = in_sizes[6];
    const int A   = in_sizes[0] / (S9 * NF);

    // ws layout: offsets[A+1] | esorted[E] | (256-align) | Mws[E][108] | Wws[E][384]
    int* offsets = (int*)d_ws;
    int* esorted = offsets + (A + 1);
    size_t ibytes = (size_t)(A + 1 + E) * sizeof(int);
    size_t moff   = (ibytes + 255) & ~(size_t)255;
    float* Mws = (float*)((char*)d_ws + moff);
    float* Wws = Mws + (size_t)E * MSZ;

    csr_kernel<<<1, 1024, 0, stream>>>(idx_i, E, A, offsets, esorted);

    so3_edge_kernel<<<(E + 3) / 4, 256, 0, stream>>>(
        radial, dir, cutoff, Wf, bf, cg_vals,
        cg_i1, cg_i2, cg_i3, ncg, E, Mws, Wws);

    so3_gather_kernel<<<A, 128, 0, stream>>>(
        x, Mws, Wws, idx_j, offsets, esorted, (float*)d_out);
}